// Round 12
// baseline (40.589 us; speedup 1.0000x reference)
//
#include <hip/hip_runtime.h>
#include <math.h>

// SPD logm -> 2x2 avg-pool -> expm via matrix polynomials on fp16 MFMA.
// p(T) = T*q(Z) + r(Z), Z = T^2 (Paterson-Stockmeyer); q,r register-only,
// r(Z) enters as the MFMA C-initializer. Single fp16 operands (~9e-3 worst
// case chain error << 3.36e-2 threshold; measured at the 0.0078 floor).
// Round 12: R5 compute + global_load_lds DMA prefetch of the NEXT matrix's
// raw f32 into a 16 KB LDS staging buffer (zero VGPRs held across barriers
// -> no spill path). 8 matrices/block, grid 1024 = 4 blocks/CU resident,
// zero block turnover. vmcnt(0)+barrier only after the ~3us compute chain.

typedef __attribute__((ext_vector_type(8))) _Float16 f16x8;
typedef __attribute__((ext_vector_type(4))) _Float16 f16x4;
typedef __attribute__((ext_vector_type(2))) _Float16 f16x2;
typedef __attribute__((ext_vector_type(4))) float f32x4;

constexpr int THREADS = 256;
constexpr int MATS_PER_BLOCK = 8;

struct Coeffs {
  float b[6];  // logm monomial coeffs (degree 5), Chebyshev fit on [1,6]
  float c[6];  // expm Taylor 1/k!
};

// byte offset of (r,c): 64x64 f16, 128B rows, 16B-granule XOR swizzle
__device__ __forceinline__ int swz64(int r, int c) {
  return r * 128 + ((((c >> 3) ^ r) & 7) << 4) + ((c & 7) << 1);
}
// 32x32 f16, 64B rows, 4 granules
__device__ __forceinline__ int swz32(int r, int c) {
  return r * 64 + ((((c >> 3) ^ r) & 3) << 4) + ((c & 7) << 1);
}

__device__ __forceinline__ f16x4 cvt4(float a, float b, float c, float d) {
  f16x4 v;
  v[0] = (_Float16)a; v[1] = (_Float16)b; v[2] = (_Float16)c; v[3] = (_Float16)d;
  return v;
}

__global__ __launch_bounds__(THREADS, 4) void spd_fp16dma_kernel(
    const float* __restrict__ A, float* __restrict__ out, Coeffs co) {
  __shared__ __align__(16) char smem[40960];
  char* TB = smem;           // 64x64 f16 T          (8 KB)
  char* ZB = smem + 8192;    // Z = T^2              (8 KB)
  char* QB = smem + 16384;   // Q = q(Z)             (8 KB)
  char* SG = smem + 24576;   // raw f32 staging      (16 KB, DMA target)
  char* PB  = ZB;            // 32x32 pooled P  (2 KB), live after B4
  char* ZeB = TB;            // Ze = P^2        (2 KB), live after B5
  char* QeB = TB + 2048;     // Qe = q_e(Ze)    (2 KB)

  const int tid = threadIdx.x;
  const int w  = tid >> 6;
  const int l64 = tid & 63;
  const int lm = tid & 15;
  const int lg = (tid & 63) >> 4;
  const int wr = w >> 1, wc = w & 1;
  const bool diag = (wr == wc);

  const int base = blockIdx.x * MATS_PER_BLOCK;

  // DMA: matrix mi's 16 KB raw f32 -> SG. Each wave copies 4x1KB chunks;
  // LDS dest is wave-uniform base (HW adds lane*16); global src is per-lane.
  auto prefetch = [&](int mi) {
    const float* mbase = A + (size_t)mi * 4096;
#pragma unroll
    for (int j = 0; j < 4; ++j) {
      const int chunk = (w << 2) + j;  // 0..15, 256 floats each
      __builtin_amdgcn_global_load_lds(
          (const __attribute__((address_space(1))) void*)(mbase + (chunk << 8) + (l64 << 2)),
          (__attribute__((address_space(3))) void*)(SG + (chunk << 10)), 16, 0, 0);
    }
  };

  // stage: SG (linear f32) -> T = (A - 3.5 I)/2.5 -> f16 swizzled TB
  auto stage = [&]() {
    const float invh = 0.4f;
#pragma unroll
    for (int it = 0; it < 4; ++it) {
      const int e4 = tid + (it << 8);
      float4 v = *((const float4*)SG + e4);
      const int row = e4 >> 4;
      const int c0 = (e4 & 15) << 2;
      const int d = row - c0;
      if (d == 0) v.x -= 3.5f;
      else if (d == 1) v.y -= 3.5f;
      else if (d == 2) v.z -= 3.5f;
      else if (d == 3) v.w -= 3.5f;
      *(f16x4*)(TB + swz64(row, c0)) =
          cvt4(v.x * invh, v.y * invh, v.z * invh, v.w * invh);
    }
  };

  auto mm64 = [&](const char* X, const char* Y, bool useDiag, f32x4 acc[2][2]) {
#pragma unroll
    for (int kh = 0; kh < 2; ++kh) {
      const int cb = (kh << 5) + (lg << 3);
      f16x8 a[2], b[2];
#pragma unroll
      for (int t = 0; t < 2; ++t)
        a[t] = *(const f16x8*)(X + swz64((wr << 5) + (t << 4) + lm, cb));
      if (useDiag) { b[0] = a[0]; b[1] = a[1]; }
      else {
#pragma unroll
        for (int t = 0; t < 2; ++t)
          b[t] = *(const f16x8*)(Y + swz64((wc << 5) + (t << 4) + lm, cb));
      }
#pragma unroll
      for (int ti = 0; ti < 2; ++ti)
#pragma unroll
        for (int tj = 0; tj < 2; ++tj)
          acc[ti][tj] = __builtin_amdgcn_mfma_f32_16x16x32_f16(a[ti], b[tj], acc[ti][tj], 0, 0, 0);
    }
  };
  auto mm32 = [&](const char* X, const char* Y, bool useDiag, f32x4& a4) {
    const int cb = lg << 3;
    f16x8 a = *(const f16x8*)(X + swz32((wr << 4) + lm, cb));
    f16x8 b;
    if (useDiag) b = a;
    else b = *(const f16x8*)(Y + swz32((wc << 4) + lm, cb));
    a4 = __builtin_amdgcn_mfma_f32_16x16x32_f16(a, b, a4, 0, 0, 0);
  };

  // full compute chain for the matrix staged in TB; writes Om
  auto compute = [&](float* __restrict__ Om) {
    // ---- mm1: Z = T*T ; write Z f16 transposed ----
    f32x4 Z[2][2];
#pragma unroll
    for (int ti = 0; ti < 2; ++ti)
#pragma unroll
      for (int tj = 0; tj < 2; ++tj) Z[ti][tj] = f32x4{0.f, 0.f, 0.f, 0.f};
    mm64(TB, TB, diag, Z);
#pragma unroll
    for (int ti = 0; ti < 2; ++ti)
#pragma unroll
      for (int tj = 0; tj < 2; ++tj) {
        const int row0 = (wr << 5) + (ti << 4) + (lg << 2);
        const int colB = (wc << 5) + (tj << 4) + lm;
        *(f16x4*)(ZB + swz64(colB, row0)) =
            cvt4(Z[ti][tj][0], Z[ti][tj][1], Z[ti][tj][2], Z[ti][tj][3]);
      }
    __syncthreads();  // B2

    // ---- mm2: Z2 = Z*Z ; Q = b5 Z2 + b3 Z + b1 I ; RP = b4 Z2 + b2 Z + b0 I ----
    f32x4 Z2[2][2];
#pragma unroll
    for (int ti = 0; ti < 2; ++ti)
#pragma unroll
      for (int tj = 0; tj < 2; ++tj) Z2[ti][tj] = f32x4{0.f, 0.f, 0.f, 0.f};
    mm64(ZB, ZB, diag, Z2);
    f32x4 RP[2][2];
#pragma unroll
    for (int ti = 0; ti < 2; ++ti)
#pragma unroll
      for (int tj = 0; tj < 2; ++tj) {
        const int row0 = (wr << 5) + (ti << 4) + (lg << 2);
        const int colB = (wc << 5) + (tj << 4) + lm;
        float qv[4];
#pragma unroll
        for (int r = 0; r < 4; ++r) {
          const float dq = (row0 + r == colB) ? co.b[1] : 0.0f;
          const float dr = (row0 + r == colB) ? co.b[0] : 0.0f;
          qv[r] = fmaf(co.b[5], Z2[ti][tj][r], fmaf(co.b[3], Z[ti][tj][r], dq));
          RP[ti][tj][r] = fmaf(co.b[4], Z2[ti][tj][r], fmaf(co.b[2], Z[ti][tj][r], dr));
        }
        *(f16x4*)(QB + swz64(colB, row0)) = cvt4(qv[0], qv[1], qv[2], qv[3]);
      }
    __syncthreads();  // B3

    // ---- mm3: L = T*Q + RP ; fused 2x2 pooling -> P (f16, overlays ZB) ----
    mm64(TB, QB, false, RP);
#pragma unroll
    for (int ti = 0; ti < 2; ++ti)
#pragma unroll
      for (int tj = 0; tj < 2; ++tj) {
        const float vs0 = RP[ti][tj][0] + RP[ti][tj][1];
        const float vs1 = RP[ti][tj][2] + RP[ti][tj][3];
        const float hs0 = vs0 + __shfl_xor(vs0, 1);
        const float hs1 = vs1 + __shfl_xor(vs1, 1);
        if ((lm & 1) == 0) {
          const int pr = (wr << 4) + (ti << 3) + (lg << 1);
          const int pc = (wc << 4) + (tj << 3) + (lm >> 1);
          f16x2 p;
          p[0] = (_Float16)(0.25f * hs0);
          p[1] = (_Float16)(0.25f * hs1);
          *(f16x2*)(PB + swz32(pc, pr)) = p;  // transposed (symmetric)
        }
      }
    __syncthreads();  // B4

    const int prow0 = (wr << 4) + (lg << 2);
    const int pcol = (wc << 4) + lm;

    // Ze = P*P (regs) ; write f16 transposed into ZeB (overlays TB)
    f32x4 Ze = f32x4{0.f, 0.f, 0.f, 0.f};
    mm32(PB, PB, diag, Ze);
    *(f16x4*)(ZeB + swz32(pcol, prow0)) = cvt4(Ze[0], Ze[1], Ze[2], Ze[3]);
    __syncthreads();  // B5

    // Z2e = Ze*Ze ; Qe = c5 Z2e + c3 Ze + c1 I ; RPe = c4 Z2e + c2 Ze + c0 I
    f32x4 Z2e = f32x4{0.f, 0.f, 0.f, 0.f};
    mm32(ZeB, ZeB, diag, Z2e);
    f32x4 RPe;
    {
      float qv[4];
#pragma unroll
      for (int r = 0; r < 4; ++r) {
        const float dq = (prow0 + r == pcol) ? co.c[1] : 0.0f;
        const float dr = (prow0 + r == pcol) ? co.c[0] : 0.0f;
        qv[r] = fmaf(co.c[5], Z2e[r], fmaf(co.c[3], Ze[r], dq));
        RPe[r] = fmaf(co.c[4], Z2e[r], fmaf(co.c[2], Ze[r], dr));
      }
      *(f16x4*)(QeB + swz32(pcol, prow0)) = cvt4(qv[0], qv[1], qv[2], qv[3]);
    }
    __syncthreads();  // B6

    // out = P*Qe + RPe -> global (transposed float4; result symmetric)
    mm32(PB, QeB, false, RPe);
    *(float4*)&Om[pcol * 32 + prow0] = make_float4(RPe[0], RPe[1], RPe[2], RPe[3]);
  };

  // ---- prologue: DMA matrix 0 into SG ----
  prefetch(base);
  asm volatile("s_waitcnt vmcnt(0)" ::: "memory");
  __syncthreads();

  for (int i = 0; i < MATS_PER_BLOCK; ++i) {
    stage();           // SG -> TB (consumes SG)
    __syncthreads();   // B1: TB visible to all waves; SG fully consumed
    if (i + 1 < MATS_PER_BLOCK) prefetch(base + i + 1);  // DMA next, in flight
    compute(out + (size_t)(base + i) * 1024);
    __syncthreads();   // B7: all LDS reads of this matrix done (TB/ZB reuse)
    if (i + 1 < MATS_PER_BLOCK) {
      asm volatile("s_waitcnt vmcnt(0)" ::: "memory");  // own DMA writes landed
      __syncthreads();  // all waves' SG chunks visible
    }
  }
}

static void make_coeffs(Coeffs* co) {
  const int DEG = 5;
  const double center = 3.5, half = 2.5;  // spectrum [1,6]
  const double r = half / center;
  const double w = (1.0 - sqrt(1.0 - r * r)) / r;
  double a[6] = {0};
  a[0] = log(center) - log1p(w * w);
  double wk = 1.0;
  for (int k = 1; k <= DEG; ++k) {
    wk *= w;
    a[k] = 2.0 * ((k & 1) ? 1.0 : -1.0) * wk / k;
  }
  double Tc[6][6] = {{0}};
  Tc[0][0] = 1.0;
  Tc[1][1] = 1.0;
  for (int j = 2; j <= DEG; ++j)
    for (int k = 0; k < 6; ++k)
      Tc[j][k] = 2.0 * (k > 0 ? Tc[j - 1][k - 1] : 0.0) - Tc[j - 2][k];
  double b[6] = {0};
  for (int j = 0; j <= DEG; ++j)
    for (int k = 0; k <= j; ++k)
      b[k] += a[j] * Tc[j][k];
  double fact = 1.0;
  for (int k = 0; k < 6; ++k) {
    co->b[k] = (float)b[k];
    co->c[k] = (float)(1.0 / fact);
    fact *= (double)(k + 1);
  }
}

extern "C" void kernel_launch(void* const* d_in, const int* in_sizes, int n_in,
                              void* d_out, int out_size, void* d_ws, size_t ws_size,
                              hipStream_t stream) {
  Coeffs co;
  make_coeffs(&co);
  const float* A = (const float*)d_in[0];
  float* out = (float*)d_out;
  const int nmat = in_sizes[0] / 4096;  // 8192
  hipLaunchKernelGGL(spd_fp16dma_kernel, dim3(nmat / MATS_PER_BLOCK), dim3(THREADS),
                     0, stream, A, out, co);
}

// Round 13
// 38.575 us; speedup vs baseline: 1.0522x; 1.0522x over previous
//
#include <hip/hip_runtime.h>
#include <math.h>

// SPD logm -> 2x2 avg-pool -> expm via matrix polynomials on fp16 MFMA.
// p(T) = T*q(Z) + r(Z), Z = T^2 (Paterson-Stockmeyer); q,r register-only,
// r(Z) enters as the MFMA C-initializer. Single fp16 operands (~9e-3 worst
// case chain error << 3.36e-2 threshold; measured at the 0.0078 floor).
// FINAL (= round-8 best, 38.97 us): one matrix per 256-thread block, 24 KB
// LDS, launch_bounds(256,6). Roofline evidence: five structurally distinct
// designs (4-wave, 6-block-occupancy, 1-wave/zero-barrier, register
// prefetch, global_load_lds DMA prefetch) all land at 39-40 us -> the
// 134 MB f32 input + 33.5 MB output stream at ~4.3 TB/s effective is the
// practical floor for this op; compute/LDS/MFMA are off the critical path.

typedef __attribute__((ext_vector_type(8))) _Float16 f16x8;
typedef __attribute__((ext_vector_type(4))) _Float16 f16x4;
typedef __attribute__((ext_vector_type(2))) _Float16 f16x2;
typedef __attribute__((ext_vector_type(4))) float f32x4;

constexpr int THREADS = 256;

struct Coeffs {
  float b[6];  // logm monomial coeffs (degree 5), Chebyshev fit on [1,6]
  float c[6];  // expm Taylor 1/k!
};

// byte offset of (r,c): 64x64 f16, 128B rows, 16B-granule XOR swizzle
__device__ __forceinline__ int swz64(int r, int c) {
  return r * 128 + ((((c >> 3) ^ r) & 7) << 4) + ((c & 7) << 1);
}
// 32x32 f16, 64B rows, 4 granules
__device__ __forceinline__ int swz32(int r, int c) {
  return r * 64 + ((((c >> 3) ^ r) & 3) << 4) + ((c & 7) << 1);
}

__device__ __forceinline__ f16x4 cvt4(float a, float b, float c, float d) {
  f16x4 v;
  v[0] = (_Float16)a; v[1] = (_Float16)b; v[2] = (_Float16)c; v[3] = (_Float16)d;
  return v;
}

__global__ __launch_bounds__(THREADS, 6) void spd_fp16o6_kernel(
    const float* __restrict__ A, float* __restrict__ out, Coeffs co) {
  __shared__ __align__(16) char smem[24576];
  char* TB = smem;           // 64x64 f16 T          (8 KB)
  char* ZB = smem + 8192;    // Z = T^2              (8 KB)
  char* QB = smem + 16384;   // Q = q(Z)             (8 KB)
  char* PB  = ZB;            // 32x32 pooled P  (2 KB), live after B4
  char* ZeB = TB;            // Ze = P^2        (2 KB), live after B5
  char* QeB = TB + 2048;     // Qe = q_e(Ze)    (2 KB)

  const int tid = threadIdx.x;
  const float* __restrict__ Am = A + (size_t)blockIdx.x * 4096;
  float* __restrict__ Om = out + (size_t)blockIdx.x * 1024;

  const int w  = tid >> 6;
  const int lm = tid & 15;
  const int lg = (tid & 63) >> 4;
  const int wr = w >> 1, wc = w & 1;
  const bool diag = (wr == wc);

  // ---- Phase 0: T = (A - 3.5 I)/2.5 -> f16 swizzled ----
  {
    const float invh = 0.4f;
#pragma unroll
    for (int it = 0; it < 4; ++it) {
      const int e4 = tid + (it << 8);
      float4 v = ((const float4*)Am)[e4];
      const int row = e4 >> 4;
      const int c0 = (e4 & 15) << 2;
      const int d = row - c0;
      if (d == 0) v.x -= 3.5f;
      else if (d == 1) v.y -= 3.5f;
      else if (d == 2) v.z -= 3.5f;
      else if (d == 3) v.w -= 3.5f;
      *(f16x4*)(TB + swz64(row, c0)) =
          cvt4(v.x * invh, v.y * invh, v.z * invh, v.w * invh);
    }
  }
  __syncthreads();  // B1

  auto mm64 = [&](const char* X, const char* Y, bool useDiag, f32x4 acc[2][2]) {
#pragma unroll
    for (int kh = 0; kh < 2; ++kh) {
      const int cb = (kh << 5) + (lg << 3);
      f16x8 a[2], b[2];
#pragma unroll
      for (int t = 0; t < 2; ++t)
        a[t] = *(const f16x8*)(X + swz64((wr << 5) + (t << 4) + lm, cb));
      if (useDiag) { b[0] = a[0]; b[1] = a[1]; }
      else {
#pragma unroll
        for (int t = 0; t < 2; ++t)
          b[t] = *(const f16x8*)(Y + swz64((wc << 5) + (t << 4) + lm, cb));
      }
#pragma unroll
      for (int ti = 0; ti < 2; ++ti)
#pragma unroll
        for (int tj = 0; tj < 2; ++tj)
          acc[ti][tj] = __builtin_amdgcn_mfma_f32_16x16x32_f16(a[ti], b[tj], acc[ti][tj], 0, 0, 0);
    }
  };

  // ---- mm1: Z = T*T (keep f32 regs) ; write Z f16 transposed ----
  f32x4 Z[2][2];
#pragma unroll
  for (int ti = 0; ti < 2; ++ti)
#pragma unroll
    for (int tj = 0; tj < 2; ++tj) Z[ti][tj] = f32x4{0.f, 0.f, 0.f, 0.f};
  mm64(TB, TB, diag, Z);
#pragma unroll
  for (int ti = 0; ti < 2; ++ti)
#pragma unroll
    for (int tj = 0; tj < 2; ++tj) {
      const int row0 = (wr << 5) + (ti << 4) + (lg << 2);
      const int colB = (wc << 5) + (tj << 4) + lm;
      *(f16x4*)(ZB + swz64(colB, row0)) =
          cvt4(Z[ti][tj][0], Z[ti][tj][1], Z[ti][tj][2], Z[ti][tj][3]);
    }
  __syncthreads();  // B2

  // ---- mm2: Z2 = Z*Z ; Q = b5 Z2 + b3 Z + b1 I ; RP = b4 Z2 + b2 Z + b0 I ----
  f32x4 Z2[2][2];
#pragma unroll
  for (int ti = 0; ti < 2; ++ti)
#pragma unroll
    for (int tj = 0; tj < 2; ++tj) Z2[ti][tj] = f32x4{0.f, 0.f, 0.f, 0.f};
  mm64(ZB, ZB, diag, Z2);
  f32x4 RP[2][2];
#pragma unroll
  for (int ti = 0; ti < 2; ++ti)
#pragma unroll
    for (int tj = 0; tj < 2; ++tj) {
      const int row0 = (wr << 5) + (ti << 4) + (lg << 2);
      const int colB = (wc << 5) + (tj << 4) + lm;
      float qv[4];
#pragma unroll
      for (int r = 0; r < 4; ++r) {
        const float dq = (row0 + r == colB) ? co.b[1] : 0.0f;
        const float dr = (row0 + r == colB) ? co.b[0] : 0.0f;
        qv[r] = fmaf(co.b[5], Z2[ti][tj][r], fmaf(co.b[3], Z[ti][tj][r], dq));
        RP[ti][tj][r] = fmaf(co.b[4], Z2[ti][tj][r], fmaf(co.b[2], Z[ti][tj][r], dr));
      }
      *(f16x4*)(QB + swz64(colB, row0)) = cvt4(qv[0], qv[1], qv[2], qv[3]);
    }
  __syncthreads();  // B3

  // ---- mm3: L = T*Q + RP ; fused 2x2 pooling -> P (f16, overlays ZB) ----
  mm64(TB, QB, false, RP);
#pragma unroll
  for (int ti = 0; ti < 2; ++ti)
#pragma unroll
    for (int tj = 0; tj < 2; ++tj) {
      const float vs0 = RP[ti][tj][0] + RP[ti][tj][1];
      const float vs1 = RP[ti][tj][2] + RP[ti][tj][3];
      const float hs0 = vs0 + __shfl_xor(vs0, 1);
      const float hs1 = vs1 + __shfl_xor(vs1, 1);
      if ((lm & 1) == 0) {
        const int pr = (wr << 4) + (ti << 3) + (lg << 1);
        const int pc = (wc << 4) + (tj << 3) + (lm >> 1);
        f16x2 p;
        p[0] = (_Float16)(0.25f * hs0);
        p[1] = (_Float16)(0.25f * hs1);
        *(f16x2*)(PB + swz32(pc, pr)) = p;  // transposed (symmetric)
      }
    }
  __syncthreads();  // B4

  // ---- expm phase on 32x32 P: one 16x16 tile per wave ----
  auto mm32 = [&](const char* X, const char* Y, bool useDiag, f32x4& a4) {
    const int cb = lg << 3;
    f16x8 a = *(const f16x8*)(X + swz32((wr << 4) + lm, cb));
    f16x8 b;
    if (useDiag) b = a;
    else b = *(const f16x8*)(Y + swz32((wc << 4) + lm, cb));
    a4 = __builtin_amdgcn_mfma_f32_16x16x32_f16(a, b, a4, 0, 0, 0);
  };

  const int prow0 = (wr << 4) + (lg << 2);
  const int pcol = (wc << 4) + lm;

  // Ze = P*P (regs) ; write f16 transposed into ZeB (overlays TB)
  f32x4 Ze = f32x4{0.f, 0.f, 0.f, 0.f};
  mm32(PB, PB, diag, Ze);
  *(f16x4*)(ZeB + swz32(pcol, prow0)) = cvt4(Ze[0], Ze[1], Ze[2], Ze[3]);
  __syncthreads();  // B5

  // Z2e = Ze*Ze ; Qe = c5 Z2e + c3 Ze + c1 I ; RPe = c4 Z2e + c2 Ze + c0 I
  f32x4 Z2e = f32x4{0.f, 0.f, 0.f, 0.f};
  mm32(ZeB, ZeB, diag, Z2e);
  f32x4 RPe;
  {
    float qv[4];
#pragma unroll
    for (int r = 0; r < 4; ++r) {
      const float dq = (prow0 + r == pcol) ? co.c[1] : 0.0f;
      const float dr = (prow0 + r == pcol) ? co.c[0] : 0.0f;
      qv[r] = fmaf(co.c[5], Z2e[r], fmaf(co.c[3], Ze[r], dq));
      RPe[r] = fmaf(co.c[4], Z2e[r], fmaf(co.c[2], Ze[r], dr));
    }
    *(f16x4*)(QeB + swz32(pcol, prow0)) = cvt4(qv[0], qv[1], qv[2], qv[3]);
  }
  __syncthreads();  // B6

  // out = P*Qe + RPe -> global (transposed float4; result symmetric)
  mm32(PB, QeB, false, RPe);
  *(float4*)&Om[pcol * 32 + prow0] = make_float4(RPe[0], RPe[1], RPe[2], RPe[3]);
}

static void make_coeffs(Coeffs* co) {
  const int DEG = 5;
  const double center = 3.5, half = 2.5;  // spectrum [1,6]
  const double r = half / center;
  const double w = (1.0 - sqrt(1.0 - r * r)) / r;
  double a[6] = {0};
  a[0] = log(center) - log1p(w * w);
  double wk = 1.0;
  for (int k = 1; k <= DEG; ++k) {
    wk *= w;
    a[k] = 2.0 * ((k & 1) ? 1.0 : -1.0) * wk / k;
  }
  double Tc[6][6] = {{0}};
  Tc[0][0] = 1.0;
  Tc[1][1] = 1.0;
  for (int j = 2; j <= DEG; ++j)
    for (int k = 0; k < 6; ++k)
      Tc[j][k] = 2.0 * (k > 0 ? Tc[j - 1][k - 1] : 0.0) - Tc[j - 2][k];
  double b[6] = {0};
  for (int j = 0; j <= DEG; ++j)
    for (int k = 0; k <= j; ++k)
      b[k] += a[j] * Tc[j][k];
  double fact = 1.0;
  for (int k = 0; k < 6; ++k) {
    co->b[k] = (float)b[k];
    co->c[k] = (float)(1.0 / fact);
    fact *= (double)(k + 1);
  }
}

extern "C" void kernel_launch(void* const* d_in, const int* in_sizes, int n_in,
                              void* d_out, int out_size, void* d_ws, size_t ws_size,
                              hipStream_t stream) {
  Coeffs co;
  make_coeffs(&co);
  const float* A = (const float*)d_in[0];
  float* out = (float*)d_out;
  const int nmat = in_sizes[0] / 4096;  // 8192
  hipLaunchKernelGGL(spd_fp16o6_kernel, dim3(nmat), dim3(THREADS), 0, stream,
                     A, out, co);
}